// Round 20
// baseline (60.261 us; speedup 1.0000x reference)
//
#include <hip/hip_runtime.h>
#include <hip/hip_bf16.h>
#include <cmath>

#define NTOK 4096
#define NBLK 256

typedef float        f32x16 __attribute__((ext_vector_type(16)));
typedef short        s16x8  __attribute__((ext_vector_type(8)));
typedef unsigned int u32x4  __attribute__((ext_vector_type(4)));

__device__ __forceinline__ unsigned short f2bf(float f) {
    __hip_bfloat16 h = __float2bfloat16(f);
    return *reinterpret_cast<unsigned short*>(&h);
}
__device__ __forceinline__ float bf2f(unsigned short u) {
    __hip_bfloat16 h = *reinterpret_cast<__hip_bfloat16*>(&u);
    return __bfloat162float(h);
}
// packed f32x2 -> bf16x2 via HIP intrinsic (lowers to v_cvt_pk_bf16_f32)
__device__ __forceinline__ unsigned pk2(float a, float b) {
    __hip_bfloat162 h = __float22bfloat162_rn(make_float2(a, b));
    return *reinterpret_cast<unsigned*>(&h);
}

// ---------------------------------------------------------------------------
// FUSED persistent kernel, take 2.  R19's regression root-caused by counters:
// bare __launch_bounds__(1024) let the compiler target 8 waves/SIMD -> 64
// VGPR, which serialized the K/V prefetch (MfmaUtil 8%, VALUBusy 24%).
// Fix: __launch_bounds__(1024, 4) = 4 waves/EU = 1 block/CU -> 128-VGPR
// budget >= the ~112 the attn loop needs.  Everything else identical to R19
// (barrier proven correct, FETCH 12.8 MB, no spill).
// ---------------------------------------------------------------------------
__global__ __launch_bounds__(1024, 4)
void fused_kernel(const float* __restrict__ x,
                  const float* __restrict__ Wq, const float* __restrict__ bq,
                  const float* __restrict__ Wk, const float* __restrict__ bk,
                  const float* __restrict__ Wv, const float* __restrict__ bv,
                  const float* __restrict__ gamma,
                  unsigned short* qt2, unsigned short* kt2, unsigned short* vt,
                  unsigned* bar, float* __restrict__ out)
{
    __shared__ union {
        struct {
            float w[80 * 64];          // 20480 B
            float bias[80];            //   320 B
            float pacc[4][4][64][9];   // 36864 B  [cp][cq][lane][pad9]
        } p1;                          // 57664 B
        struct {
            float slds[4][64][64];     // 65536 B
            float sldl[4][64];         //  1024 B
        } p2;                          // 66560 B
    } sm;

    const int t   = threadIdx.x;       // 0..1023
    const int blk = blockIdx.x;        // 0..255
    const int lane = t & 63;
    const int wv   = t >> 6;           // 0..15

    // ======================= PHASE 1: QKV projection =======================
    {
        for (int idx = t; idx < 1280; idx += 1024) {
            const int row  = idx >> 4;
            const int col4 = idx & 15;
            const float* src = (row < 8)  ? (Wq + row * 64)
                             : (row < 16) ? (Wk + (row - 8) * 64)
                                          : (Wv + (row - 16) * 64);
            ((float4*)sm.p1.w)[idx] = ((const float4*)src)[col4];
        }
        if (t < 80)
            sm.p1.bias[t] = (t < 8) ? bq[t] : (t < 16) ? bk[t - 8] : bv[t - 16];
        __syncthreads();

        const int cq = wv & 3;         // channel quarter
        const int cp = wv >> 2;        // chunk group 0..3
        const int gid = blk * 64 + lane;
        const int b = gid >> 12;
        const int i = gid & (NTOK - 1);

        const float* xb = x + ((size_t)b * 64 + 16 * cq) * NTOK + i;
        float xv[16];
        #pragma unroll
        for (int c = 0; c < 16; c++) xv[c] = xb[(size_t)c * NTOK];

        const size_t row = (size_t)b * NTOK + i;
        const int jl   = i & 15;
        const int slot = (jl & 3) | ((jl & 4) << 1) | ((jl & 8) >> 1); // swap b2<->b3

        #pragma unroll
        for (int s = 0; s < 3; ++s) {
            const int chunk = cp + 4 * s;        // cp, cp+4, cp+8
            const bool act = (chunk < 10);
            if (act) {
                float a[8];
                #pragma unroll
                for (int o = 0; o < 8; o++) a[o] = 0.f;
                #pragma unroll
                for (int c4 = 0; c4 < 4; c4++) {
                    #pragma unroll
                    for (int o = 0; o < 8; o++) {
                        const float4 w4v =
                            ((const float4*)sm.p1.w)[(chunk * 8 + o) * 16 + cq * 4 + c4];
                        a[o] += w4v.x * xv[c4*4+0] + w4v.y * xv[c4*4+1]
                              + w4v.z * xv[c4*4+2] + w4v.w * xv[c4*4+3];
                    }
                }
                #pragma unroll
                for (int o = 0; o < 8; o++) sm.p1.pacc[cp][cq][lane][o] = a[o];
            }
            __syncthreads();
            if (act) {
                const int ob = 2 * cq;
                float fin[2];
                #pragma unroll
                for (int oo = 0; oo < 2; oo++)
                    fin[oo] = ((sm.p1.pacc[cp][0][lane][ob + oo]
                              + sm.p1.pacc[cp][1][lane][ob + oo])
                             + (sm.p1.pacc[cp][2][lane][ob + oo]
                              + sm.p1.pacc[cp][3][lane][ob + oo]))
                            + sm.p1.bias[chunk * 8 + ob + oo];

                if (chunk < 2) {
                    if (chunk == 0) {
                        const float LOG2E = 1.4426950408889634f;
                        fin[0] *= LOG2E; fin[1] *= LOG2E;
                    }
                    unsigned short hu[2], lu[2];
                    #pragma unroll
                    for (int oo = 0; oo < 2; oo++) {
                        hu[oo] = f2bf(fin[oo]);
                        lu[oo] = f2bf(fin[oo] - bf2f(hu[oo]));
                    }
                    unsigned short* dst = (chunk == 0 ? qt2 : kt2) + row * 16 + ob;
                    *(unsigned*)dst       = *(const unsigned*)hu;
                    *(unsigned*)(dst + 8) = *(const unsigned*)lu;
                } else {
                    const int cbase = (chunk - 2) * 8 + ob;
                    unsigned short* vdst =
                        vt + ((size_t)b * 256 + (i >> 4)) * 1024 + (size_t)cbase * 16 + slot;
                    vdst[0]  = f2bf(fin[0]);
                    vdst[16] = f2bf(fin[1]);
                }
            }
            if (s < 2) __syncthreads();
        }
    }

    // ======================= GRID BARRIER ==================================
    __syncthreads();
    if (t == 0) {
        __threadfence();                         // release: flush this XCD's L2
        atomicAdd(bar, 1u);                      // device-scope by default
        while (atomicOr(bar, 0u) < NBLK)         // device-scope coherent read
            __builtin_amdgcn_s_sleep(16);
        __threadfence();                         // acquire: invalidate stale lines
    }
    __syncthreads();

    // ======================= PHASE 2: attention (R17 structure) ============
    const int qt   = wv & 1;            // q-tile of this wave (pairing key)
    const int u    = wv >> 1;           // 0..7 j-range id (shared by pair)
    const int lo31 = lane & 31;
    const int h    = lane >> 5;
    const int b2    = blk >> 6;
    const int qbase = (blk & 63) << 6;  // 64 q per block
    const int j0    = u << 9;           // 512 j per wave

    const unsigned short* qrow =
        qt2 + ((size_t)b2 * NTOK + qbase + qt * 32 + lo31) * 16;
    s16x8 qB1 = *(const s16x8*)qrow;
    s16x8 qB2;
    if (h == 0) qB2 = *(const s16x8*)(qrow + 8);
    else        { u32x4 z = {0,0,0,0}; qB2 = __builtin_bit_cast(s16x8, z); }

    const unsigned short* kb  = kt2 + (size_t)b2 * NTOK * 16 + (size_t)h * 8;
    const unsigned short* vbA = vt + (size_t)b2 * NTOK * 64 + (size_t)lo31 * 16 + 8 * h;
    const unsigned short* vbB = vbA + 512;

    f32x16 accA, accB;
    #pragma unroll
    for (int r = 0; r < 16; r++) { accA[r] = 0.f; accB[r] = 0.f; }
    float lsum = 0.f;

    s16x8 K[2], V00[2], V01[2], V10[2], V11[2];

    #define LOADSET(s_, a_) do {                                              \
        K[s_]   = *(const s16x8*)(kb + (size_t)(j0 + ((a_) << 5) + lo31) * 16);  \
        V00[s_] = *(const s16x8*)(vbA + (size_t)((j0 >> 4) + ((a_) << 1)) * 1024);     \
        V01[s_] = *(const s16x8*)(vbA + (size_t)((j0 >> 4) + ((a_) << 1) + 1) * 1024); \
        V10[s_] = *(const s16x8*)(vbB + (size_t)((j0 >> 4) + ((a_) << 1)) * 1024);     \
        V11[s_] = *(const s16x8*)(vbB + (size_t)((j0 >> 4) + ((a_) << 1) + 1) * 1024); \
    } while (0)

    LOADSET(0, 0);

    #pragma unroll
    for (int it = 0; it < 16; ++it) {
        const int cu = it & 1;
        const int nx = it + 1;
        LOADSET(cu ^ 1, (nx < 16) ? nx : 0);   // issue next-chunk loads first

        f32x16 s;
        #pragma unroll
        for (int r = 0; r < 16; r++) s[r] = 0.f;
        s = __builtin_amdgcn_mfma_f32_32x32x16_bf16(K[cu], qB1, s, 0, 0, 0);
        s = __builtin_amdgcn_mfma_f32_32x32x16_bf16(K[cu], qB2, s, 0, 0, 0);

        #pragma unroll
        for (int r = 0; r < 16; r++) s[r] = __builtin_amdgcn_exp2f(s[r]);

        lsum += ((s[0]+s[1])+(s[2]+s[3])) + ((s[4]+s[5])+(s[6]+s[7]))
              + ((s[8]+s[9])+(s[10]+s[11])) + ((s[12]+s[13])+(s[14]+s[15]));

        u32x4 wa, wc;
        wa.x = pk2(s[0], s[1]);   wa.y = pk2(s[2], s[3]);
        wa.z = pk2(s[4], s[5]);   wa.w = pk2(s[6], s[7]);
        wc.x = pk2(s[8], s[9]);   wc.y = pk2(s[10], s[11]);
        wc.z = pk2(s[12], s[13]); wc.w = pk2(s[14], s[15]);
        s16x8 pf0 = __builtin_bit_cast(s16x8, wa);
        s16x8 pf1 = __builtin_bit_cast(s16x8, wc);

        __builtin_amdgcn_s_setprio(1);
        accA = __builtin_amdgcn_mfma_f32_32x32x16_bf16(V00[cu], pf0, accA, 0, 0, 0);
        accA = __builtin_amdgcn_mfma_f32_32x32x16_bf16(V01[cu], pf1, accA, 0, 0, 0);
        accB = __builtin_amdgcn_mfma_f32_32x32x16_bf16(V10[cu], pf0, accB, 0, 0, 0);
        accB = __builtin_amdgcn_mfma_f32_32x32x16_bf16(V11[cu], pf1, accB, 0, 0, 0);
        __builtin_amdgcn_s_setprio(0);
    }

    lsum += __shfl_xor(lsum, 32);

    #define WR_SLOT(sidx) do {                                                \
        const int s_ = (sidx);                                                \
        _Pragma("unroll")                                                     \
        for (int r = 0; r < 16; r++) {                                        \
            const int c_ = (r & 3) + 8 * (r >> 2) + 4 * h;                    \
            sm.p2.slds[s_][c_][qt * 32 + lo31]      = accA[r];                \
            sm.p2.slds[s_][c_ + 32][qt * 32 + lo31] = accB[r];                \
        }                                                                     \
        if (h == 0) sm.p2.sldl[s_][qt * 32 + lo31] = lsum;                    \
    } while (0)

    #define MRG_SLOT(sidx) do {                                               \
        const int s_ = (sidx);                                                \
        _Pragma("unroll")                                                     \
        for (int r = 0; r < 16; r++) {                                        \
            const int c_ = (r & 3) + 8 * (r >> 2) + 4 * h;                    \
            accA[r] += sm.p2.slds[s_][c_][qt * 32 + lo31];                    \
            accB[r] += sm.p2.slds[s_][c_ + 32][qt * 32 + lo31];               \
        }                                                                     \
        lsum += sm.p2.sldl[s_][qt * 32 + lo31];                               \
    } while (0)

    if (u >= 4) WR_SLOT(u - 4);
    __syncthreads();
    if (u < 4) MRG_SLOT(u);
    __syncthreads();
    if (u == 2 || u == 3) WR_SLOT(u - 2);
    __syncthreads();
    if (u < 2) MRG_SLOT(u);
    __syncthreads();
    if (u == 1) WR_SLOT(0);
    __syncthreads();
    if (u == 0) { MRG_SLOT(0); WR_SLOT(0); }
    __syncthreads();

    // ---- fused epilogue: out = gamma*acc/L + x, all 1024 threads ----
    const int c  = t >> 4;              // 0..63
    const int q4 = (t & 15) << 2;       // 0,4,..,60
    const float g = gamma[0];
    const float4 a4 = *(const float4*)&sm.p2.slds[0][c][q4];
    const float g0 = g / sm.p2.sldl[0][q4 + 0];
    const float g1 = g / sm.p2.sldl[0][q4 + 1];
    const float g2 = g / sm.p2.sldl[0][q4 + 2];
    const float g3 = g / sm.p2.sldl[0][q4 + 3];
    const size_t off = (((size_t)b2 * 64 + c) << 12) + qbase + q4;
    const float4 xv4 = *(const float4*)(x + off);
    float4 o;
    o.x = a4.x * g0 + xv4.x;
    o.y = a4.y * g1 + xv4.y;
    o.z = a4.z * g2 + xv4.z;
    o.w = a4.w * g3 + xv4.w;
    *(float4*)(out + off) = o;
}

// ---------------------------------------------------------------------------
extern "C" void kernel_launch(void* const* d_in, const int* in_sizes, int n_in,
                              void* d_out, int out_size, void* d_ws, size_t ws_size,
                              hipStream_t stream) {
    const float* x     = (const float*)d_in[0];
    const float* Wq    = (const float*)d_in[1];
    const float* bq    = (const float*)d_in[2];
    const float* Wk    = (const float*)d_in[3];
    const float* bk    = (const float*)d_in[4];
    const float* Wv    = (const float*)d_in[5];
    const float* bv    = (const float*)d_in[6];
    const float* gamma = (const float*)d_in[7];
    float* out = (float*)d_out;

    unsigned short* qt2 = (unsigned short*)d_ws;            // 4*4096*16 bf16
    unsigned short* kt2 = qt2 + (size_t)4 * NTOK * 16;      // 4*4096*16 bf16
    unsigned short* vt  = kt2 + (size_t)4 * NTOK * 16;      // 4*4096*64 bf16 (tiled+permuted)
    unsigned* bar = (unsigned*)(vt + (size_t)4 * 64 * NTOK); // barrier counter

    hipMemsetAsync(bar, 0, 8, stream);   // poison/replay-safe barrier reset
    fused_kernel<<<NBLK, 1024, 0, stream>>>(x, Wq, bq, Wk, bk, Wv, bv, gamma,
                                            qt2, kt2, vt, bar, out);
}

// Round 21
// 57.069 us; speedup vs baseline: 1.0559x; 1.0559x over previous
//
#include <hip/hip_runtime.h>
#include <hip/hip_bf16.h>
#include <cmath>

#define NTOK 4096
#define NBLK 256

typedef float        f32x16 __attribute__((ext_vector_type(16)));
typedef short        s16x8  __attribute__((ext_vector_type(8)));
typedef unsigned int u32x4  __attribute__((ext_vector_type(4)));

__device__ __forceinline__ unsigned short f2bf(float f) {
    __hip_bfloat16 h = __float2bfloat16(f);
    return *reinterpret_cast<unsigned short*>(&h);
}
__device__ __forceinline__ float bf2f(unsigned short u) {
    __hip_bfloat16 h = *reinterpret_cast<__hip_bfloat16*>(&u);
    return __bfloat162float(h);
}
// packed f32x2 -> bf16x2 via HIP intrinsic (lowers to v_cvt_pk_bf16_f32)
__device__ __forceinline__ unsigned pk2(float a, float b) {
    __hip_bfloat162 h = __float22bfloat162_rn(make_float2(a, b));
    return *reinterpret_cast<unsigned*>(&h);
}

// ---------------------------------------------------------------------------
// FUSED persistent kernel, take 3.  R20 counters exonerated VGPR (64 is the
// natural footprint; acc lives in unified AGPR half) and convicted the
// BARRIER: the spin was atomicOr -- an atomic RMW -- so 256 spinners
// serialized exclusively on one cache line (~2.5-5k queued RMWs during the
// arrival spread), and the last block's arrival add queued behind the storm.
// Fix: spin on an ATOMIC LOAD (agent-scope, sc-bit read served concurrently
// from the shared LLC, no line ownership), add-once release, threadfence
// acquire.  Everything else byte-identical to R20.
// ---------------------------------------------------------------------------
__global__ __launch_bounds__(1024, 4)
void fused_kernel(const float* __restrict__ x,
                  const float* __restrict__ Wq, const float* __restrict__ bq,
                  const float* __restrict__ Wk, const float* __restrict__ bk,
                  const float* __restrict__ Wv, const float* __restrict__ bv,
                  const float* __restrict__ gamma,
                  unsigned short* qt2, unsigned short* kt2, unsigned short* vt,
                  unsigned* bar, float* __restrict__ out)
{
    __shared__ union {
        struct {
            float w[80 * 64];          // 20480 B
            float bias[80];            //   320 B
            float pacc[4][4][64][9];   // 36864 B  [cp][cq][lane][pad9]
        } p1;                          // 57664 B
        struct {
            float slds[4][64][64];     // 65536 B
            float sldl[4][64];         //  1024 B
        } p2;                          // 66560 B
    } sm;

    const int t   = threadIdx.x;       // 0..1023
    const int blk = blockIdx.x;        // 0..255
    const int lane = t & 63;
    const int wv   = t >> 6;           // 0..15

    // ======================= PHASE 1: QKV projection =======================
    {
        for (int idx = t; idx < 1280; idx += 1024) {
            const int row  = idx >> 4;
            const int col4 = idx & 15;
            const float* src = (row < 8)  ? (Wq + row * 64)
                             : (row < 16) ? (Wk + (row - 8) * 64)
                                          : (Wv + (row - 16) * 64);
            ((float4*)sm.p1.w)[idx] = ((const float4*)src)[col4];
        }
        if (t < 80)
            sm.p1.bias[t] = (t < 8) ? bq[t] : (t < 16) ? bk[t - 8] : bv[t - 16];
        __syncthreads();

        const int cq = wv & 3;         // channel quarter
        const int cp = wv >> 2;        // chunk group 0..3
        const int gid = blk * 64 + lane;
        const int b = gid >> 12;
        const int i = gid & (NTOK - 1);

        const float* xb = x + ((size_t)b * 64 + 16 * cq) * NTOK + i;
        float xv[16];
        #pragma unroll
        for (int c = 0; c < 16; c++) xv[c] = xb[(size_t)c * NTOK];

        const size_t row = (size_t)b * NTOK + i;
        const int jl   = i & 15;
        const int slot = (jl & 3) | ((jl & 4) << 1) | ((jl & 8) >> 1); // swap b2<->b3

        #pragma unroll
        for (int s = 0; s < 3; ++s) {
            const int chunk = cp + 4 * s;        // cp, cp+4, cp+8
            const bool act = (chunk < 10);
            if (act) {
                float a[8];
                #pragma unroll
                for (int o = 0; o < 8; o++) a[o] = 0.f;
                #pragma unroll
                for (int c4 = 0; c4 < 4; c4++) {
                    #pragma unroll
                    for (int o = 0; o < 8; o++) {
                        const float4 w4v =
                            ((const float4*)sm.p1.w)[(chunk * 8 + o) * 16 + cq * 4 + c4];
                        a[o] += w4v.x * xv[c4*4+0] + w4v.y * xv[c4*4+1]
                              + w4v.z * xv[c4*4+2] + w4v.w * xv[c4*4+3];
                    }
                }
                #pragma unroll
                for (int o = 0; o < 8; o++) sm.p1.pacc[cp][cq][lane][o] = a[o];
            }
            __syncthreads();
            if (act) {
                const int ob = 2 * cq;
                float fin[2];
                #pragma unroll
                for (int oo = 0; oo < 2; oo++)
                    fin[oo] = ((sm.p1.pacc[cp][0][lane][ob + oo]
                              + sm.p1.pacc[cp][1][lane][ob + oo])
                             + (sm.p1.pacc[cp][2][lane][ob + oo]
                              + sm.p1.pacc[cp][3][lane][ob + oo]))
                            + sm.p1.bias[chunk * 8 + ob + oo];

                if (chunk < 2) {
                    if (chunk == 0) {
                        const float LOG2E = 1.4426950408889634f;
                        fin[0] *= LOG2E; fin[1] *= LOG2E;
                    }
                    unsigned short hu[2], lu[2];
                    #pragma unroll
                    for (int oo = 0; oo < 2; oo++) {
                        hu[oo] = f2bf(fin[oo]);
                        lu[oo] = f2bf(fin[oo] - bf2f(hu[oo]));
                    }
                    unsigned short* dst = (chunk == 0 ? qt2 : kt2) + row * 16 + ob;
                    *(unsigned*)dst       = *(const unsigned*)hu;
                    *(unsigned*)(dst + 8) = *(const unsigned*)lu;
                } else {
                    const int cbase = (chunk - 2) * 8 + ob;
                    unsigned short* vdst =
                        vt + ((size_t)b * 256 + (i >> 4)) * 1024 + (size_t)cbase * 16 + slot;
                    vdst[0]  = f2bf(fin[0]);
                    vdst[16] = f2bf(fin[1]);
                }
            }
            if (s < 2) __syncthreads();
        }
    }

    // ======================= GRID BARRIER (load-spin) ======================
    __syncthreads();
    if (t == 0) {
        // release: one RMW per block; agent scope flushes this XCD's writes
        __hip_atomic_fetch_add(bar, 1u, __ATOMIC_RELEASE, __HIP_MEMORY_SCOPE_AGENT);
        // spin on a plain agent-scope atomic LOAD (no line ownership, no RMW)
        while (__hip_atomic_load(bar, __ATOMIC_RELAXED, __HIP_MEMORY_SCOPE_AGENT) < NBLK)
            __builtin_amdgcn_s_sleep(32);
        __threadfence();               // acquire: invalidate stale cached lines
    }
    __syncthreads();

    // ======================= PHASE 2: attention (R17 structure) ============
    const int qt   = wv & 1;            // q-tile of this wave (pairing key)
    const int u    = wv >> 1;           // 0..7 j-range id (shared by pair)
    const int lo31 = lane & 31;
    const int h    = lane >> 5;
    const int b2    = blk >> 6;
    const int qbase = (blk & 63) << 6;  // 64 q per block
    const int j0    = u << 9;           // 512 j per wave

    const unsigned short* qrow =
        qt2 + ((size_t)b2 * NTOK + qbase + qt * 32 + lo31) * 16;
    s16x8 qB1 = *(const s16x8*)qrow;
    s16x8 qB2;
    if (h == 0) qB2 = *(const s16x8*)(qrow + 8);
    else        { u32x4 z = {0,0,0,0}; qB2 = __builtin_bit_cast(s16x8, z); }

    const unsigned short* kb  = kt2 + (size_t)b2 * NTOK * 16 + (size_t)h * 8;
    const unsigned short* vbA = vt + (size_t)b2 * NTOK * 64 + (size_t)lo31 * 16 + 8 * h;
    const unsigned short* vbB = vbA + 512;

    f32x16 accA, accB;
    #pragma unroll
    for (int r = 0; r < 16; r++) { accA[r] = 0.f; accB[r] = 0.f; }
    float lsum = 0.f;

    s16x8 K[2], V00[2], V01[2], V10[2], V11[2];

    #define LOADSET(s_, a_) do {                                              \
        K[s_]   = *(const s16x8*)(kb + (size_t)(j0 + ((a_) << 5) + lo31) * 16);  \
        V00[s_] = *(const s16x8*)(vbA + (size_t)((j0 >> 4) + ((a_) << 1)) * 1024);     \
        V01[s_] = *(const s16x8*)(vbA + (size_t)((j0 >> 4) + ((a_) << 1) + 1) * 1024); \
        V10[s_] = *(const s16x8*)(vbB + (size_t)((j0 >> 4) + ((a_) << 1)) * 1024);     \
        V11[s_] = *(const s16x8*)(vbB + (size_t)((j0 >> 4) + ((a_) << 1) + 1) * 1024); \
    } while (0)

    LOADSET(0, 0);

    #pragma unroll
    for (int it = 0; it < 16; ++it) {
        const int cu = it & 1;
        const int nx = it + 1;
        LOADSET(cu ^ 1, (nx < 16) ? nx : 0);   // issue next-chunk loads first

        f32x16 s;
        #pragma unroll
        for (int r = 0; r < 16; r++) s[r] = 0.f;
        s = __builtin_amdgcn_mfma_f32_32x32x16_bf16(K[cu], qB1, s, 0, 0, 0);
        s = __builtin_amdgcn_mfma_f32_32x32x16_bf16(K[cu], qB2, s, 0, 0, 0);

        #pragma unroll
        for (int r = 0; r < 16; r++) s[r] = __builtin_amdgcn_exp2f(s[r]);

        lsum += ((s[0]+s[1])+(s[2]+s[3])) + ((s[4]+s[5])+(s[6]+s[7]))
              + ((s[8]+s[9])+(s[10]+s[11])) + ((s[12]+s[13])+(s[14]+s[15]));

        u32x4 wa, wc;
        wa.x = pk2(s[0], s[1]);   wa.y = pk2(s[2], s[3]);
        wa.z = pk2(s[4], s[5]);   wa.w = pk2(s[6], s[7]);
        wc.x = pk2(s[8], s[9]);   wc.y = pk2(s[10], s[11]);
        wc.z = pk2(s[12], s[13]); wc.w = pk2(s[14], s[15]);
        s16x8 pf0 = __builtin_bit_cast(s16x8, wa);
        s16x8 pf1 = __builtin_bit_cast(s16x8, wc);

        __builtin_amdgcn_s_setprio(1);
        accA = __builtin_amdgcn_mfma_f32_32x32x16_bf16(V00[cu], pf0, accA, 0, 0, 0);
        accA = __builtin_amdgcn_mfma_f32_32x32x16_bf16(V01[cu], pf1, accA, 0, 0, 0);
        accB = __builtin_amdgcn_mfma_f32_32x32x16_bf16(V10[cu], pf0, accB, 0, 0, 0);
        accB = __builtin_amdgcn_mfma_f32_32x32x16_bf16(V11[cu], pf1, accB, 0, 0, 0);
        __builtin_amdgcn_s_setprio(0);
    }

    lsum += __shfl_xor(lsum, 32);

    #define WR_SLOT(sidx) do {                                                \
        const int s_ = (sidx);                                                \
        _Pragma("unroll")                                                     \
        for (int r = 0; r < 16; r++) {                                        \
            const int c_ = (r & 3) + 8 * (r >> 2) + 4 * h;                    \
            sm.p2.slds[s_][c_][qt * 32 + lo31]      = accA[r];                \
            sm.p2.slds[s_][c_ + 32][qt * 32 + lo31] = accB[r];                \
        }                                                                     \
        if (h == 0) sm.p2.sldl[s_][qt * 32 + lo31] = lsum;                    \
    } while (0)

    #define MRG_SLOT(sidx) do {                                               \
        const int s_ = (sidx);                                                \
        _Pragma("unroll")                                                     \
        for (int r = 0; r < 16; r++) {                                        \
            const int c_ = (r & 3) + 8 * (r >> 2) + 4 * h;                    \
            accA[r] += sm.p2.slds[s_][c_][qt * 32 + lo31];                    \
            accB[r] += sm.p2.slds[s_][c_ + 32][qt * 32 + lo31];               \
        }                                                                     \
        lsum += sm.p2.sldl[s_][qt * 32 + lo31];                               \
    } while (0)

    if (u >= 4) WR_SLOT(u - 4);
    __syncthreads();
    if (u < 4) MRG_SLOT(u);
    __syncthreads();
    if (u == 2 || u == 3) WR_SLOT(u - 2);
    __syncthreads();
    if (u < 2) MRG_SLOT(u);
    __syncthreads();
    if (u == 1) WR_SLOT(0);
    __syncthreads();
    if (u == 0) { MRG_SLOT(0); WR_SLOT(0); }
    __syncthreads();

    // ---- fused epilogue: out = gamma*acc/L + x, all 1024 threads ----
    const int c  = t >> 4;              // 0..63
    const int q4 = (t & 15) << 2;       // 0,4,..,60
    const float g = gamma[0];
    const float4 a4 = *(const float4*)&sm.p2.slds[0][c][q4];
    const float g0 = g / sm.p2.sldl[0][q4 + 0];
    const float g1 = g / sm.p2.sldl[0][q4 + 1];
    const float g2 = g / sm.p2.sldl[0][q4 + 2];
    const float g3 = g / sm.p2.sldl[0][q4 + 3];
    const size_t off = (((size_t)b2 * 64 + c) << 12) + qbase + q4;
    const float4 xv4 = *(const float4*)(x + off);
    float4 o;
    o.x = a4.x * g0 + xv4.x;
    o.y = a4.y * g1 + xv4.y;
    o.z = a4.z * g2 + xv4.z;
    o.w = a4.w * g3 + xv4.w;
    *(float4*)(out + off) = o;
}

// ---------------------------------------------------------------------------
extern "C" void kernel_launch(void* const* d_in, const int* in_sizes, int n_in,
                              void* d_out, int out_size, void* d_ws, size_t ws_size,
                              hipStream_t stream) {
    const float* x     = (const float*)d_in[0];
    const float* Wq    = (const float*)d_in[1];
    const float* bq    = (const float*)d_in[2];
    const float* Wk    = (const float*)d_in[3];
    const float* bk    = (const float*)d_in[4];
    const float* Wv    = (const float*)d_in[5];
    const float* bv    = (const float*)d_in[6];
    const float* gamma = (const float*)d_in[7];
    float* out = (float*)d_out;

    unsigned short* qt2 = (unsigned short*)d_ws;            // 4*4096*16 bf16
    unsigned short* kt2 = qt2 + (size_t)4 * NTOK * 16;      // 4*4096*16 bf16
    unsigned short* vt  = kt2 + (size_t)4 * NTOK * 16;      // 4*4096*64 bf16 (tiled+permuted)
    unsigned* bar = (unsigned*)(vt + (size_t)4 * 64 * NTOK); // barrier counter

    hipMemsetAsync(bar, 0, 8, stream);   // poison/replay-safe barrier reset
    fused_kernel<<<NBLK, 1024, 0, stream>>>(x, Wq, bq, Wk, bk, Wv, bv, gamma,
                                            qt2, kt2, vt, bar, out);
}

// Round 22
// 33.822 us; speedup vs baseline: 1.7817x; 1.6873x over previous
//
#include <hip/hip_runtime.h>
#include <hip/hip_bf16.h>
#include <cmath>

#define NTOK 4096

typedef float        f32x16 __attribute__((ext_vector_type(16)));
typedef short        s16x8  __attribute__((ext_vector_type(8)));
typedef unsigned int u32x4  __attribute__((ext_vector_type(4)));

__device__ __forceinline__ unsigned short f2bf(float f) {
    __hip_bfloat16 h = __float2bfloat16(f);
    return *reinterpret_cast<unsigned short*>(&h);
}
__device__ __forceinline__ float bf2f(unsigned short u) {
    __hip_bfloat16 h = *reinterpret_cast<__hip_bfloat16*>(&u);
    return __bfloat162float(h);
}
// packed f32x2 -> bf16x2 via HIP intrinsic (lowers to v_cvt_pk_bf16_f32)
__device__ __forceinline__ unsigned pk2(float a, float b) {
    __hip_bfloat162 h = __float22bfloat162_rn(make_float2(a, b));
    return *reinterpret_cast<unsigned*>(&h);
}

// ---------------------------------------------------------------------------
// Kernel 1: QKV projection v2 — 5x chunk-reuse, x read ONCE.
// R18's version read x 5x (20 MB) with only 2 chunks of FMA per 16-load
// slice.  Now: 512 blocks x 512 thr (8 waves, 2 blocks/CU); block = 32
// voxels.  Wave wv -> (cq = wv&3 channel quarter, cp = wv>>2); lane ->
// (voxel v = l&31, half hh = l>>5).  xv[16] loaded once, feeds 5 chunks
// {cp, cp+2, cp+4, cp+6, cp+8}: 320 FMA per 16 strided loads, x traffic
// 4 MB total (1x).  Per chunk: thread computes outputs [4hh,4hh+4) over
// its 16 channels -> padded LDS pacc[cp][cq][v][9] -> cross-cq reduce by
// thread (o = 2cq+hh, voxel v) -> store.  Output formats unchanged:
// qt2/kt2[b][i][16]=[hi|lo] (q log2e-scaled), vt[b][i/16][c][sigma(i%16)].
// ---------------------------------------------------------------------------
__global__ __launch_bounds__(512)
void qkv_kernel(const float* __restrict__ x,
                const float* __restrict__ Wq, const float* __restrict__ bq,
                const float* __restrict__ Wk, const float* __restrict__ bk,
                const float* __restrict__ Wv, const float* __restrict__ bv,
                unsigned short* __restrict__ qt2, unsigned short* __restrict__ kt2,
                unsigned short* __restrict__ vt)
{
    __shared__ float wlds[80 * 64];      // all 80 weight rows, 20 KB
    __shared__ float blds[80];
    __shared__ float pacc[2][4][32][9];  // [cp][cq][v][8+pad]

    const int t  = threadIdx.x;          // 0..511
    const int l  = t & 63;
    const int wv = t >> 6;               // 0..7
    const int cq = wv & 3;               // channel quarter
    const int cp = wv >> 2;              // 0..1 chunk-parity group
    const int v  = l & 31;               // voxel within 32-group
    const int hh = l >> 5;               // output half

    // stage all weights + biases (512 threads x 2.5 rounds of float4)
    for (int idx = t; idx < 1280; idx += 512) {
        const int row  = idx >> 4;
        const int col4 = idx & 15;
        const float* src = (row < 8)  ? (Wq + row * 64)
                         : (row < 16) ? (Wk + (row - 8) * 64)
                                      : (Wv + (row - 16) * 64);
        ((float4*)wlds)[idx] = ((const float4*)src)[col4];
    }
    if (t < 80)
        blds[t] = (t < 8) ? bq[t] : (t < 16) ? bk[t - 8] : bv[t - 16];
    __syncthreads();

    const int vg = blockIdx.x;           // 0..511
    const int b  = vg >> 7;
    const int i  = ((vg & 127) << 5) + v;

    // xv[16]: channels [16cq, 16cq+16) of voxel i (lanes hh=0/1 duplicate
    // addresses -> coalescer-merged)
    const float* xb = x + ((size_t)b * 64 + 16 * cq) * NTOK + i;
    float xv[16];
    #pragma unroll
    for (int c = 0; c < 16; c++) xv[c] = xb[(size_t)c * NTOK];

    const size_t row = (size_t)b * NTOK + i;
    const int jl   = i & 15;
    const int slot = (jl & 3) | ((jl & 4) << 1) | ((jl & 8) >> 1);  // swap b2<->b3

    #pragma unroll
    for (int s = 0; s < 5; ++s) {
        const int chunk = cp + 2 * s;    // cp=0: 0,2,4,6,8  cp=1: 1,3,5,7,9

        // partial: outputs [4hh, 4hh+4) over channels [16cq, 16cq+16)
        float a[4];
        #pragma unroll
        for (int k = 0; k < 4; k++) a[k] = 0.f;
        #pragma unroll
        for (int c4 = 0; c4 < 4; c4++) {
            #pragma unroll
            for (int k = 0; k < 4; k++) {
                const float4 w4v =
                    ((const float4*)wlds)[(chunk * 8 + 4 * hh + k) * 16 + cq * 4 + c4];
                a[k] += w4v.x * xv[c4*4+0] + w4v.y * xv[c4*4+1]
                      + w4v.z * xv[c4*4+2] + w4v.w * xv[c4*4+3];
            }
        }
        if (s) __syncthreads();          // pacc free from previous chunk
        #pragma unroll
        for (int k = 0; k < 4; k++) pacc[cp][cq][v][4 * hh + k] = a[k];
        __syncthreads();

        // reduce + store: this thread owns (voxel v, output o = 2cq+hh)
        const int o = 2 * cq + hh;
        float fin = ((pacc[cp][0][v][o] + pacc[cp][1][v][o])
                  +  (pacc[cp][2][v][o] + pacc[cp][3][v][o]))
                  + blds[chunk * 8 + o];

        if (chunk < 2) {
            if (chunk == 0) fin *= 1.4426950408889634f;   // log2e into q
            const unsigned short hu = f2bf(fin);
            const unsigned short lu = f2bf(fin - bf2f(hu));
            unsigned short* dst = (chunk == 0 ? qt2 : kt2) + row * 16;
            dst[o]     = hu;
            dst[8 + o] = lu;
        } else {
            const int c = (chunk - 2) * 8 + o;
            vt[((size_t)b * 256 + (i >> 4)) * 1024 + (size_t)c * 16 + slot] = f2bf(fin);
        }
    }
}

// ---------------------------------------------------------------------------
// Kernel 2: fused flash attention with WAVE-PAIRING — BYTE-IDENTICAL to R17
// (the proven winner; fusion attempts R19-R21 all regressed and are closed).
// ---------------------------------------------------------------------------
__global__ __launch_bounds__(1024)
void attn_kernel(const unsigned short* __restrict__ qt2,
                 const unsigned short* __restrict__ kt2,
                 const unsigned short* __restrict__ vt,
                 const float* __restrict__ x,
                 const float* __restrict__ gamma,
                 float* __restrict__ out)
{
    __shared__ float slds[4][64][64];   // merge slots [c][q 0..63], 64 KB
    __shared__ float sldl[4][64];       // l per slot

    const int t    = threadIdx.x;       // 0..1023
    const int l    = t & 63;
    const int wv   = t >> 6;            // 0..15
    const int qt   = wv & 1;            // q-tile of this wave (pairing key)
    const int u    = wv >> 1;           // 0..7 j-range id (shared by pair)
    const int lo31 = l & 31;
    const int h    = l >> 5;
    const int w     = blockIdx.x;
    const int b     = w >> 6;
    const int qbase = (w & 63) << 6;    // 64 q per block
    const int j0    = u << 9;           // 512 j per wave

    const unsigned short* qrow =
        qt2 + ((size_t)b * NTOK + qbase + qt * 32 + lo31) * 16;
    s16x8 qB1 = *(const s16x8*)qrow;
    s16x8 qB2;
    if (h == 0) qB2 = *(const s16x8*)(qrow + 8);
    else        { u32x4 z = {0,0,0,0}; qB2 = __builtin_bit_cast(s16x8, z); }

    const unsigned short* kb  = kt2 + (size_t)b * NTOK * 16 + (size_t)h * 8;
    const unsigned short* vbA = vt + (size_t)b * NTOK * 64 + (size_t)lo31 * 16 + 8 * h;
    const unsigned short* vbB = vbA + 512;

    f32x16 accA, accB;
    #pragma unroll
    for (int r = 0; r < 16; r++) { accA[r] = 0.f; accB[r] = 0.f; }
    float lsum = 0.f;

    s16x8 K[2], V00[2], V01[2], V10[2], V11[2];

    #define LOADSET(s_, a_) do {                                              \
        K[s_]   = *(const s16x8*)(kb + (size_t)(j0 + ((a_) << 5) + lo31) * 16);  \
        V00[s_] = *(const s16x8*)(vbA + (size_t)((j0 >> 4) + ((a_) << 1)) * 1024);     \
        V01[s_] = *(const s16x8*)(vbA + (size_t)((j0 >> 4) + ((a_) << 1) + 1) * 1024); \
        V10[s_] = *(const s16x8*)(vbB + (size_t)((j0 >> 4) + ((a_) << 1)) * 1024);     \
        V11[s_] = *(const s16x8*)(vbB + (size_t)((j0 >> 4) + ((a_) << 1) + 1) * 1024); \
    } while (0)

    LOADSET(0, 0);

    #pragma unroll
    for (int it = 0; it < 16; ++it) {
        const int cu = it & 1;
        const int nx = it + 1;
        LOADSET(cu ^ 1, (nx < 16) ? nx : 0);   // issue next-chunk loads first

        f32x16 s;
        #pragma unroll
        for (int r = 0; r < 16; r++) s[r] = 0.f;
        s = __builtin_amdgcn_mfma_f32_32x32x16_bf16(K[cu], qB1, s, 0, 0, 0);
        s = __builtin_amdgcn_mfma_f32_32x32x16_bf16(K[cu], qB2, s, 0, 0, 0);

        #pragma unroll
        for (int r = 0; r < 16; r++) s[r] = __builtin_amdgcn_exp2f(s[r]);

        lsum += ((s[0]+s[1])+(s[2]+s[3])) + ((s[4]+s[5])+(s[6]+s[7]))
              + ((s[8]+s[9])+(s[10]+s[11])) + ((s[12]+s[13])+(s[14]+s[15]));

        u32x4 wa, wc;
        wa.x = pk2(s[0], s[1]);   wa.y = pk2(s[2], s[3]);
        wa.z = pk2(s[4], s[5]);   wa.w = pk2(s[6], s[7]);
        wc.x = pk2(s[8], s[9]);   wc.y = pk2(s[10], s[11]);
        wc.z = pk2(s[12], s[13]); wc.w = pk2(s[14], s[15]);
        s16x8 pf0 = __builtin_bit_cast(s16x8, wa);
        s16x8 pf1 = __builtin_bit_cast(s16x8, wc);

        __builtin_amdgcn_s_setprio(1);
        accA = __builtin_amdgcn_mfma_f32_32x32x16_bf16(V00[cu], pf0, accA, 0, 0, 0);
        accA = __builtin_amdgcn_mfma_f32_32x32x16_bf16(V01[cu], pf1, accA, 0, 0, 0);
        accB = __builtin_amdgcn_mfma_f32_32x32x16_bf16(V10[cu], pf0, accB, 0, 0, 0);
        accB = __builtin_amdgcn_mfma_f32_32x32x16_bf16(V11[cu], pf1, accB, 0, 0, 0);
        __builtin_amdgcn_s_setprio(0);
    }

    lsum += __shfl_xor(lsum, 32);

    #define WR_SLOT(sidx) do {                                                \
        const int s_ = (sidx);                                                \
        _Pragma("unroll")                                                     \
        for (int r = 0; r < 16; r++) {                                        \
            const int c_ = (r & 3) + 8 * (r >> 2) + 4 * h;                    \
            slds[s_][c_][qt * 32 + lo31]      = accA[r];                      \
            slds[s_][c_ + 32][qt * 32 + lo31] = accB[r];                      \
        }                                                                     \
        if (h == 0) sldl[s_][qt * 32 + lo31] = lsum;                          \
    } while (0)

    #define MRG_SLOT(sidx) do {                                               \
        const int s_ = (sidx);                                                \
        _Pragma("unroll")                                                     \
        for (int r = 0; r < 16; r++) {                                        \
            const int c_ = (r & 3) + 8 * (r >> 2) + 4 * h;                    \
            accA[r] += slds[s_][c_][qt * 32 + lo31];                          \
            accB[r] += slds[s_][c_ + 32][qt * 32 + lo31];                     \
        }                                                                     \
        lsum += sldl[s_][qt * 32 + lo31];                                     \
    } while (0)

    if (u >= 4) WR_SLOT(u - 4);
    __syncthreads();
    if (u < 4) MRG_SLOT(u);
    __syncthreads();
    if (u == 2 || u == 3) WR_SLOT(u - 2);
    __syncthreads();
    if (u < 2) MRG_SLOT(u);
    __syncthreads();
    if (u == 1) WR_SLOT(0);
    __syncthreads();
    if (u == 0) { MRG_SLOT(0); WR_SLOT(0); }
    __syncthreads();

    // ---- fused epilogue: out = gamma*acc/L + x, all 1024 threads ----
    const int c  = t >> 4;              // 0..63
    const int q4 = (t & 15) << 2;       // 0,4,..,60
    const float g = gamma[0];
    const float4 a4 = *(const float4*)&slds[0][c][q4];
    const float g0 = g / sldl[0][q4 + 0];
    const float g1 = g / sldl[0][q4 + 1];
    const float g2 = g / sldl[0][q4 + 2];
    const float g3 = g / sldl[0][q4 + 3];
    const size_t off = (((size_t)b * 64 + c) << 12) + qbase + q4;
    const float4 xv4 = *(const float4*)(x + off);
    float4 o;
    o.x = a4.x * g0 + xv4.x;
    o.y = a4.y * g1 + xv4.y;
    o.z = a4.z * g2 + xv4.z;
    o.w = a4.w * g3 + xv4.w;
    *(float4*)(out + off) = o;
}

// ---------------------------------------------------------------------------
extern "C" void kernel_launch(void* const* d_in, const int* in_sizes, int n_in,
                              void* d_out, int out_size, void* d_ws, size_t ws_size,
                              hipStream_t stream) {
    const float* x     = (const float*)d_in[0];
    const float* Wq    = (const float*)d_in[1];
    const float* bq    = (const float*)d_in[2];
    const float* Wk    = (const float*)d_in[3];
    const float* bk    = (const float*)d_in[4];
    const float* Wv    = (const float*)d_in[5];
    const float* bv    = (const float*)d_in[6];
    const float* gamma = (const float*)d_in[7];
    float* out = (float*)d_out;

    unsigned short* qt2 = (unsigned short*)d_ws;            // 4*4096*16 bf16
    unsigned short* kt2 = qt2 + (size_t)4 * NTOK * 16;      // 4*4096*16 bf16
    unsigned short* vt  = kt2 + (size_t)4 * NTOK * 16;      // 4*4096*64 bf16 (tiled+permuted)

    qkv_kernel<<<512, 512, 0, stream>>>(x, Wq, bq, Wk, bk, Wv, bv, qt2, kt2, vt);
    attn_kernel<<<256, 1024, 0, stream>>>(qt2, kt2, vt, x, gamma, out);
}

// Round 23
// 31.966 us; speedup vs baseline: 1.8852x; 1.0581x over previous
//
#include <hip/hip_runtime.h>
#include <hip/hip_bf16.h>
#include <cmath>

#define NTOK 4096

typedef float        f32x16 __attribute__((ext_vector_type(16)));
typedef short        s16x8  __attribute__((ext_vector_type(8)));
typedef unsigned int u32x4  __attribute__((ext_vector_type(4)));

__device__ __forceinline__ unsigned short f2bf(float f) {
    __hip_bfloat16 h = __float2bfloat16(f);
    return *reinterpret_cast<unsigned short*>(&h);
}
__device__ __forceinline__ float bf2f(unsigned short u) {
    __hip_bfloat16 h = *reinterpret_cast<__hip_bfloat16*>(&u);
    return __bfloat162float(h);
}
// packed f32x2 -> bf16x2 via HIP intrinsic (lowers to v_cvt_pk_bf16_f32)
__device__ __forceinline__ unsigned pk2(float a, float b) {
    __hip_bfloat162 h = __float22bfloat162_rn(make_float2(a, b));
    return *reinterpret_cast<unsigned*>(&h);
}

// ---------------------------------------------------------------------------
// Kernel 1: QKV projection, 5-part x 2-chunk x c-split-4 (R18 champion,
// restored verbatim).  Grid 1280 = part*256 + vg (XCD = vg%8 pinned), 256
// thr (4 waves = c-quarters), 5120 waves = 5/SIMD, every lane loads
// DISTINCT voxel data (full 256B utility per load instruction — the v2
// rewrite's duplicated-address halving was the R22 regression).  xv[16]
// loaded once, feeds 2 chunks.  Padded-LDS pacc reduce across c-quarters.
// Outputs: qt2/kt2[b][i][16]=[hi|lo] (q log2e-scaled),
// vt[b][i/16][c][sigma(i%16)] j-tiled + slot-permuted (sigma = swap b2<->b3)
// so the attention PV B-frag is a direct repack of the S^T C/D fragment.
// ---------------------------------------------------------------------------
__global__ __launch_bounds__(256)
void qkv_kernel(const float* __restrict__ x,
                const float* __restrict__ Wq, const float* __restrict__ bq,
                const float* __restrict__ Wk, const float* __restrict__ bk,
                const float* __restrict__ Wv, const float* __restrict__ bv,
                unsigned short* __restrict__ qt2, unsigned short* __restrict__ kt2,
                unsigned short* __restrict__ vt)
{
    __shared__ float wlds[16 * 64];      // this part's 16 weight rows (4 KB)
    __shared__ float blds[16];
    __shared__ float pacc[4][64][9];     // per-wave partials, padded

    const int t    = threadIdx.x;        // 0..255
    const int lane = t & 63;             // voxel within group
    const int wv   = t >> 6;             // 0..3 (c-quarter)
    const int part = blockIdx.x >> 8;    // 0..4
    const int vg   = blockIdx.x & 255;

    // stage this part's 16 weight rows + biases
    {
        const int row  = t >> 4;             // 0..15
        const int col4 = t & 15;
        const int g    = part * 16 + row;
        const float* src = (g < 8)  ? (Wq + g * 64)
                         : (g < 16) ? (Wk + (g - 8) * 64)
                                    : (Wv + (g - 16) * 64);
        ((float4*)wlds)[t] = ((const float4*)src)[col4];
        if (t < 16) {
            const int gg = part * 16 + t;
            blds[t] = (gg < 8) ? bq[gg] : (gg < 16) ? bk[gg - 8] : bv[gg - 16];
        }
    }
    __syncthreads();

    const int gid = vg * 64 + lane;
    const int b = gid >> 12;
    const int i = gid & (NTOK - 1);

    // wave wv covers channels [16*wv, 16*wv+16) -- loaded ONCE, used 2x
    const float* xb = x + ((size_t)b * 64 + 16 * wv) * NTOK + i;
    float xv[16];
    #pragma unroll
    for (int c = 0; c < 16; c++) xv[c] = xb[(size_t)c * NTOK];

    const size_t row = (size_t)b * NTOK + i;
    const int jl   = i & 15;
    const int slot = (jl & 3) | ((jl & 4) << 1) | ((jl & 8) >> 1);  // swap b2<->b3

    #pragma unroll
    for (int ch = 0; ch < 2; ch++) {
        const int chunk = part * 2 + ch;

        float a[8];
        #pragma unroll
        for (int o = 0; o < 8; o++) a[o] = 0.f;
        #pragma unroll
        for (int c4 = 0; c4 < 4; c4++) {
            #pragma unroll
            for (int o = 0; o < 8; o++) {
                const float4 wv4 = ((const float4*)wlds)[(ch * 8 + o) * 16 + wv * 4 + c4];
                a[o] += wv4.x * xv[c4*4+0] + wv4.y * xv[c4*4+1]
                      + wv4.z * xv[c4*4+2] + wv4.w * xv[c4*4+3];
            }
        }
        if (ch) __syncthreads();         // pacc free from previous chunk
        #pragma unroll
        for (int o = 0; o < 8; o++) pacc[wv][lane][o] = a[o];
        __syncthreads();

        // epilogue: thread = (voxel = lane, outputs o in [2*wv, 2*wv+2))
        const int ob = 2 * wv;
        float fin[2];
        #pragma unroll
        for (int oo = 0; oo < 2; oo++)
            fin[oo] = ((pacc[0][lane][ob + oo] + pacc[1][lane][ob + oo])
                    +  (pacc[2][lane][ob + oo] + pacc[3][lane][ob + oo]))
                    + blds[ch * 8 + ob + oo];

        if (chunk < 2) {
            if (chunk == 0) {
                const float LOG2E = 1.4426950408889634f;
                fin[0] *= LOG2E; fin[1] *= LOG2E;
            }
            unsigned short hu[2], lu[2];
            #pragma unroll
            for (int oo = 0; oo < 2; oo++) {
                hu[oo] = f2bf(fin[oo]);
                lu[oo] = f2bf(fin[oo] - bf2f(hu[oo]));
            }
            unsigned short* dst = (chunk == 0 ? qt2 : kt2) + row * 16 + ob;
            *(unsigned*)dst       = *(const unsigned*)hu;
            *(unsigned*)(dst + 8) = *(const unsigned*)lu;
        } else {
            const int cbase = (chunk - 2) * 8 + ob;
            unsigned short* vdst =
                vt + ((size_t)b * 256 + (i >> 4)) * 1024 + (size_t)cbase * 16 + slot;
            vdst[0]  = f2bf(fin[0]);
            vdst[16] = f2bf(fin[1]);
        }
    }
}

// ---------------------------------------------------------------------------
// Kernel 2: fused flash attention with WAVE-PAIRING (R17 champion, restored
// verbatim).  16 waves/block on a 64-q tile; waves (2k,2k+1) share j-range
// [k*512,k*512+512) but different q-tiles -> the pair issues IDENTICAL K/V
// addresses and the trailing wave hits L1 -> L2-side K/V traffic halves,
// per-wave registers stay at the lean 32q level.  Grid 256 (1 block/CU).
// No-max exp2 softmax (CQ=8 bounds |s|), zero cross-lane j-loop (j-permuted
// V^T layout), per-q-tile additive LDS merge, fused epilogue.
// ---------------------------------------------------------------------------
__global__ __launch_bounds__(1024)
void attn_kernel(const unsigned short* __restrict__ qt2,
                 const unsigned short* __restrict__ kt2,
                 const unsigned short* __restrict__ vt,
                 const float* __restrict__ x,
                 const float* __restrict__ gamma,
                 float* __restrict__ out)
{
    __shared__ float slds[4][64][64];   // merge slots [c][q 0..63], 64 KB
    __shared__ float sldl[4][64];       // l per slot

    const int t    = threadIdx.x;       // 0..1023
    const int l    = t & 63;
    const int wv   = t >> 6;            // 0..15
    const int qt   = wv & 1;            // q-tile of this wave (pairing key)
    const int u    = wv >> 1;           // 0..7 j-range id (shared by pair)
    const int lo31 = l & 31;
    const int h    = l >> 5;
    const int w     = blockIdx.x;
    const int b     = w >> 6;
    const int qbase = (w & 63) << 6;    // 64 q per block
    const int j0    = u << 9;           // 512 j per wave

    const unsigned short* qrow =
        qt2 + ((size_t)b * NTOK + qbase + qt * 32 + lo31) * 16;
    s16x8 qB1 = *(const s16x8*)qrow;
    s16x8 qB2;
    if (h == 0) qB2 = *(const s16x8*)(qrow + 8);
    else        { u32x4 z = {0,0,0,0}; qB2 = __builtin_bit_cast(s16x8, z); }

    const unsigned short* kb  = kt2 + (size_t)b * NTOK * 16 + (size_t)h * 8;
    const unsigned short* vbA = vt + (size_t)b * NTOK * 64 + (size_t)lo31 * 16 + 8 * h;
    const unsigned short* vbB = vbA + 512;

    f32x16 accA, accB;
    #pragma unroll
    for (int r = 0; r < 16; r++) { accA[r] = 0.f; accB[r] = 0.f; }
    float lsum = 0.f;

    s16x8 K[2], V00[2], V01[2], V10[2], V11[2];

    #define LOADSET(s_, a_) do {                                              \
        K[s_]   = *(const s16x8*)(kb + (size_t)(j0 + ((a_) << 5) + lo31) * 16);  \
        V00[s_] = *(const s16x8*)(vbA + (size_t)((j0 >> 4) + ((a_) << 1)) * 1024);     \
        V01[s_] = *(const s16x8*)(vbA + (size_t)((j0 >> 4) + ((a_) << 1) + 1) * 1024); \
        V10[s_] = *(const s16x8*)(vbB + (size_t)((j0 >> 4) + ((a_) << 1)) * 1024);     \
        V11[s_] = *(const s16x8*)(vbB + (size_t)((j0 >> 4) + ((a_) << 1) + 1) * 1024); \
    } while (0)

    LOADSET(0, 0);

    #pragma unroll
    for (int it = 0; it < 16; ++it) {
        const int cu = it & 1;
        const int nx = it + 1;
        LOADSET(cu ^ 1, (nx < 16) ? nx : 0);   // issue next-chunk loads first

        f32x16 s;
        #pragma unroll
        for (int r = 0; r < 16; r++) s[r] = 0.f;
        s = __builtin_amdgcn_mfma_f32_32x32x16_bf16(K[cu], qB1, s, 0, 0, 0);
        s = __builtin_amdgcn_mfma_f32_32x32x16_bf16(K[cu], qB2, s, 0, 0, 0);

        // ---- p = exp2(s) raw (no max needed: CQ=8 keeps |s| small) ----
        #pragma unroll
        for (int r = 0; r < 16; r++) s[r] = __builtin_amdgcn_exp2f(s[r]);

        lsum += ((s[0]+s[1])+(s[2]+s[3])) + ((s[4]+s[5])+(s[6]+s[7]))
              + ((s[8]+s[9])+(s[10]+s[11])) + ((s[12]+s[13])+(s[14]+s[15]));

        // ---- P^T -> B-frags: direct repack of own registers ----
        u32x4 wa, wc;
        wa.x = pk2(s[0], s[1]);   wa.y = pk2(s[2], s[3]);
        wa.z = pk2(s[4], s[5]);   wa.w = pk2(s[6], s[7]);
        wc.x = pk2(s[8], s[9]);   wc.y = pk2(s[10], s[11]);
        wc.z = pk2(s[12], s[13]); wc.w = pk2(s[14], s[15]);
        s16x8 pf0 = __builtin_bit_cast(s16x8, wa);
        s16x8 pf1 = __builtin_bit_cast(s16x8, wc);

        __builtin_amdgcn_s_setprio(1);
        accA = __builtin_amdgcn_mfma_f32_32x32x16_bf16(V00[cu], pf0, accA, 0, 0, 0);
        accA = __builtin_amdgcn_mfma_f32_32x32x16_bf16(V01[cu], pf1, accA, 0, 0, 0);
        accB = __builtin_amdgcn_mfma_f32_32x32x16_bf16(V10[cu], pf0, accB, 0, 0, 0);
        accB = __builtin_amdgcn_mfma_f32_32x32x16_bf16(V11[cu], pf1, accB, 0, 0, 0);
        __builtin_amdgcn_s_setprio(0);
    }

    lsum += __shfl_xor(lsum, 32);

    #define WR_SLOT(sidx) do {                                                \
        const int s_ = (sidx);                                                \
        _Pragma("unroll")                                                     \
        for (int r = 0; r < 16; r++) {                                        \
            const int c_ = (r & 3) + 8 * (r >> 2) + 4 * h;                    \
            slds[s_][c_][qt * 32 + lo31]      = accA[r];                      \
            slds[s_][c_ + 32][qt * 32 + lo31] = accB[r];                      \
        }                                                                     \
        if (h == 0) sldl[s_][qt * 32 + lo31] = lsum;                          \
    } while (0)

    #define MRG_SLOT(sidx) do {                                               \
        const int s_ = (sidx);                                                \
        _Pragma("unroll")                                                     \
        for (int r = 0; r < 16; r++) {                                        \
            const int c_ = (r & 3) + 8 * (r >> 2) + 4 * h;                    \
            accA[r] += slds[s_][c_][qt * 32 + lo31];                          \
            accB[r] += slds[s_][c_ + 32][qt * 32 + lo31];                     \
        }                                                                     \
        lsum += sldl[s_][qt * 32 + lo31];                                     \
    } while (0)

    if (u >= 4) WR_SLOT(u - 4);
    __syncthreads();
    if (u < 4) MRG_SLOT(u);
    __syncthreads();
    if (u == 2 || u == 3) WR_SLOT(u - 2);
    __syncthreads();
    if (u < 2) MRG_SLOT(u);
    __syncthreads();
    if (u == 1) WR_SLOT(0);
    __syncthreads();
    if (u == 0) { MRG_SLOT(0); WR_SLOT(0); }
    __syncthreads();

    // ---- fused epilogue: out = gamma*acc/L + x, all 1024 threads ----
    const int c  = t >> 4;              // 0..63
    const int q4 = (t & 15) << 2;       // 0,4,..,60
    const float g = gamma[0];
    const float4 a4 = *(const float4*)&slds[0][c][q4];
    const float g0 = g / sldl[0][q4 + 0];
    const float g1 = g / sldl[0][q4 + 1];
    const float g2 = g / sldl[0][q4 + 2];
    const float g3 = g / sldl[0][q4 + 3];
    const size_t off = (((size_t)b * 64 + c) << 12) + qbase + q4;
    const float4 xv4 = *(const float4*)(x + off);
    float4 o;
    o.x = a4.x * g0 + xv4.x;
    o.y = a4.y * g1 + xv4.y;
    o.z = a4.z * g2 + xv4.z;
    o.w = a4.w * g3 + xv4.w;
    *(float4*)(out + off) = o;
}

// ---------------------------------------------------------------------------
extern "C" void kernel_launch(void* const* d_in, const int* in_sizes, int n_in,
                              void* d_out, int out_size, void* d_ws, size_t ws_size,
                              hipStream_t stream) {
    const float* x     = (const float*)d_in[0];
    const float* Wq    = (const float*)d_in[1];
    const float* bq    = (const float*)d_in[2];
    const float* Wk    = (const float*)d_in[3];
    const float* bk    = (const float*)d_in[4];
    const float* Wv    = (const float*)d_in[5];
    const float* bv    = (const float*)d_in[6];
    const float* gamma = (const float*)d_in[7];
    float* out = (float*)d_out;

    unsigned short* qt2 = (unsigned short*)d_ws;            // 4*4096*16 bf16
    unsigned short* kt2 = qt2 + (size_t)4 * NTOK * 16;      // 4*4096*16 bf16
    unsigned short* vt  = kt2 + (size_t)4 * NTOK * 16;      // 4*4096*64 bf16 (tiled+permuted)

    qkv_kernel<<<1280, 256, 0, stream>>>(x, Wq, bq, Wk, bk, Wv, bv, qt2, kt2, vt);
    attn_kernel<<<256, 1024, 0, stream>>>(qt2, kt2, vt, x, gamma, out);
}

// Round 25
// 31.306 us; speedup vs baseline: 1.9249x; 1.0211x over previous
//
#include <hip/hip_runtime.h>
#include <hip/hip_bf16.h>
#include <cmath>

#define NTOK 4096

typedef float        f32x16 __attribute__((ext_vector_type(16)));
typedef short        s16x8  __attribute__((ext_vector_type(8)));
typedef unsigned int u32x4  __attribute__((ext_vector_type(4)));

__device__ __forceinline__ unsigned short f2bf(float f) {
    __hip_bfloat16 h = __float2bfloat16(f);
    return *reinterpret_cast<unsigned short*>(&h);
}
__device__ __forceinline__ float bf2f(unsigned short u) {
    __hip_bfloat16 h = *reinterpret_cast<__hip_bfloat16*>(&u);
    return __bfloat162float(h);
}
// packed f32x2 -> bf16x2 via HIP intrinsic (lowers to v_cvt_pk_bf16_f32)
__device__ __forceinline__ unsigned pk2(float a, float b) {
    __hip_bfloat162 h = __float22bfloat162_rn(make_float2(a, b));
    return *reinterpret_cast<unsigned*>(&h);
}

// ---------------------------------------------------------------------------
// Kernel 1: QKV projection via MFMA.  R24 crashed on a grid bug: 512 blocks
// with b = blk>>5 drove b to 15 (OOB x reads).  Each block = 4 waves x 32
// voxels = 128 voxels; 16384 voxels -> GRID 128 (fixed).  0.5 waves/SIMD,
// but each wave's 56 VMEM loads are independent (single latency hit), then
// 12 MFMA.  O[96x64 padded] @ x[64x16384]; fragment layouts copied from the
// attn-kernel-verified mappings (A row=l&31 k=8h+e; B col=l&31 same k;
// C/D col=l&31 row=(r&3)+8(r>>2)+4h).  Stores byte-identical formats:
// qt2/kt2[b][i][16]=[hi|lo] (q log2e-scaled), vt[b][i/16][c][sigma(i%16)].
// ---------------------------------------------------------------------------
__global__ __launch_bounds__(256, 4)
void qkv_kernel(const float* __restrict__ x,
                const float* __restrict__ Wq, const float* __restrict__ bq,
                const float* __restrict__ Wk, const float* __restrict__ bk,
                const float* __restrict__ Wv, const float* __restrict__ bv,
                unsigned short* __restrict__ qt2, unsigned short* __restrict__ kt2,
                unsigned short* __restrict__ vt)
{
    const int t    = threadIdx.x;
    const int l    = t & 63;
    const int wv   = t >> 6;            // 0..3: col-tile within block
    const int lo31 = l & 31;
    const int h    = l >> 5;
    const int blk  = blockIdx.x;        // 0..127
    const int b    = blk >> 5;          // 0..3
    const int i    = ((blk & 31) << 7) + (wv << 5) + lo31;   // 0..4095

    // ---- B-frags: x_bf16[k = 16ks+8h .. +8][vox=i], 4 K-steps ----
    const float* xb = x + ((size_t)b * 64) * NTOK + i;
    s16x8 B0, B1, B2, B3;
    #define MAKE_B(Bv, ks) do {                                               \
        const float* src = xb + (size_t)((ks) * 16 + 8 * h) * NTOK;           \
        float f0 = src[0];                  float f1 = src[NTOK];             \
        float f2 = src[2 * (size_t)NTOK];   float f3 = src[3 * (size_t)NTOK]; \
        float f4 = src[4 * (size_t)NTOK];   float f5 = src[5 * (size_t)NTOK]; \
        float f6 = src[6 * (size_t)NTOK];   float f7 = src[7 * (size_t)NTOK]; \
        u32x4 p;                                                              \
        p.x = pk2(f0, f1); p.y = pk2(f2, f3);                                 \
        p.z = pk2(f4, f5); p.w = pk2(f6, f7);                                 \
        Bv = __builtin_bit_cast(s16x8, p);                                    \
    } while (0)
    MAKE_B(B0, 0); MAKE_B(B1, 1); MAKE_B(B2, 2); MAKE_B(B3, 3);

    // ---- 3 row-tiles: A-frags from W (L2-hot), accumulate over K ----
    f32x16 C0, C1, C2;
    #pragma unroll
    for (int r = 0; r < 16; r++) { C0[r] = 0.f; C1[r] = 0.f; C2[r] = 0.f; }

    #pragma unroll
    for (int tile = 0; tile < 3; tile++) {
        const int row = tile * 32 + lo31;
        const bool act = (row < 80);
        const float* wrow = (row < 8)  ? (Wq + row * 64)
                          : (row < 16) ? (Wk + (row - 8) * 64)
                          : act        ? (Wv + (row - 16) * 64)
                                       : Wq;              // inert, loads guarded
        #pragma unroll
        for (int ks = 0; ks < 4; ks++) {
            u32x4 p;
            if (act) {
                const float4 f0 = ((const float4*)(wrow + ks * 16 + 8 * h))[0];
                const float4 f1 = ((const float4*)(wrow + ks * 16 + 8 * h))[1];
                p.x = pk2(f0.x, f0.y); p.y = pk2(f0.z, f0.w);
                p.z = pk2(f1.x, f1.y); p.w = pk2(f1.z, f1.w);
            } else { p.x = 0; p.y = 0; p.z = 0; p.w = 0; }
            const s16x8 A = __builtin_bit_cast(s16x8, p);
            const s16x8 Bk = (ks == 0) ? B0 : (ks == 1) ? B1 : (ks == 2) ? B2 : B3;
            if (tile == 0)      C0 = __builtin_amdgcn_mfma_f32_32x32x16_bf16(A, Bk, C0, 0, 0, 0);
            else if (tile == 1) C1 = __builtin_amdgcn_mfma_f32_32x32x16_bf16(A, Bk, C1, 0, 0, 0);
            else                C2 = __builtin_amdgcn_mfma_f32_32x32x16_bf16(A, Bk, C2, 0, 0, 0);
        }
    }

    // ---- epilogue: store in the existing formats ----
    const size_t rowq = ((size_t)b * NTOK + i) * 16;
    const int jl   = i & 15;
    const int slot = (jl & 3) | ((jl & 4) << 1) | ((jl & 8) >> 1);  // swap b2<->b3
    const size_t vbase = ((size_t)b * 256 + (i >> 4)) * 1024 + slot;

    #pragma unroll
    for (int tile = 0; tile < 3; tile++) {
        #pragma unroll
        for (int r = 0; r < 16; r++) {
            const int grow = tile * 32 + (r & 3) + 8 * (r >> 2) + 4 * h;
            const float cval = (tile == 0) ? C0[r] : (tile == 1) ? C1[r] : C2[r];
            if (grow < 8) {
                const float fin = (cval + bq[grow]) * 1.4426950408889634f;
                const unsigned short hu = f2bf(fin);
                qt2[rowq + grow]     = hu;
                qt2[rowq + 8 + grow] = f2bf(fin - bf2f(hu));
            } else if (grow < 16) {
                const int o = grow - 8;
                const float fin = cval + bk[o];
                const unsigned short hu = f2bf(fin);
                kt2[rowq + o]     = hu;
                kt2[rowq + 8 + o] = f2bf(fin - bf2f(hu));
            } else if (grow < 80) {
                const int c = grow - 16;
                vt[vbase + (size_t)c * 16] = f2bf(cval + bv[c]);
            }
        }
    }
}

// ---------------------------------------------------------------------------
// Kernel 2: fused flash attention with WAVE-PAIRING (champion, verbatim).
// ---------------------------------------------------------------------------
__global__ __launch_bounds__(1024)
void attn_kernel(const unsigned short* __restrict__ qt2,
                 const unsigned short* __restrict__ kt2,
                 const unsigned short* __restrict__ vt,
                 const float* __restrict__ x,
                 const float* __restrict__ gamma,
                 float* __restrict__ out)
{
    __shared__ float slds[4][64][64];   // merge slots [c][q 0..63], 64 KB
    __shared__ float sldl[4][64];       // l per slot

    const int t    = threadIdx.x;       // 0..1023
    const int l    = t & 63;
    const int wv   = t >> 6;            // 0..15
    const int qt   = wv & 1;            // q-tile of this wave (pairing key)
    const int u    = wv >> 1;           // 0..7 j-range id (shared by pair)
    const int lo31 = l & 31;
    const int h    = l >> 5;
    const int w     = blockIdx.x;
    const int b     = w >> 6;
    const int qbase = (w & 63) << 6;    // 64 q per block
    const int j0    = u << 9;           // 512 j per wave

    const unsigned short* qrow =
        qt2 + ((size_t)b * NTOK + qbase + qt * 32 + lo31) * 16;
    s16x8 qB1 = *(const s16x8*)qrow;
    s16x8 qB2;
    if (h == 0) qB2 = *(const s16x8*)(qrow + 8);
    else        { u32x4 z = {0,0,0,0}; qB2 = __builtin_bit_cast(s16x8, z); }

    const unsigned short* kb  = kt2 + (size_t)b * NTOK * 16 + (size_t)h * 8;
    const unsigned short* vbA = vt + (size_t)b * NTOK * 64 + (size_t)lo31 * 16 + 8 * h;
    const unsigned short* vbB = vbA + 512;

    f32x16 accA, accB;
    #pragma unroll
    for (int r = 0; r < 16; r++) { accA[r] = 0.f; accB[r] = 0.f; }
    float lsum = 0.f;

    s16x8 K[2], V00[2], V01[2], V10[2], V11[2];

    #define LOADSET(s_, a_) do {                                              \
        K[s_]   = *(const s16x8*)(kb + (size_t)(j0 + ((a_) << 5) + lo31) * 16);  \
        V00[s_] = *(const s16x8*)(vbA + (size_t)((j0 >> 4) + ((a_) << 1)) * 1024);     \
        V01[s_] = *(const s16x8*)(vbA + (size_t)((j0 >> 4) + ((a_) << 1) + 1) * 1024); \
        V10[s_] = *(const s16x8*)(vbB + (size_t)((j0 >> 4) + ((a_) << 1)) * 1024);     \
        V11[s_] = *(const s16x8*)(vbB + (size_t)((j0 >> 4) + ((a_) << 1) + 1) * 1024); \
    } while (0)

    LOADSET(0, 0);

    #pragma unroll
    for (int it = 0; it < 16; ++it) {
        const int cu = it & 1;
        const int nx = it + 1;
        LOADSET(cu ^ 1, (nx < 16) ? nx : 0);   // issue next-chunk loads first

        f32x16 s;
        #pragma unroll
        for (int r = 0; r < 16; r++) s[r] = 0.f;
        s = __builtin_amdgcn_mfma_f32_32x32x16_bf16(K[cu], qB1, s, 0, 0, 0);
        s = __builtin_amdgcn_mfma_f32_32x32x16_bf16(K[cu], qB2, s, 0, 0, 0);

        // ---- p = exp2(s) raw (no max needed: CQ=8 keeps |s| small) ----
        #pragma unroll
        for (int r = 0; r < 16; r++) s[r] = __builtin_amdgcn_exp2f(s[r]);

        lsum += ((s[0]+s[1])+(s[2]+s[3])) + ((s[4]+s[5])+(s[6]+s[7]))
              + ((s[8]+s[9])+(s[10]+s[11])) + ((s[12]+s[13])+(s[14]+s[15]));

        // ---- P^T -> B-frags: direct repack of own registers ----
        u32x4 wa, wc;
        wa.x = pk2(s[0], s[1]);   wa.y = pk2(s[2], s[3]);
        wa.z = pk2(s[4], s[5]);   wa.w = pk2(s[6], s[7]);
        wc.x = pk2(s[8], s[9]);   wc.y = pk2(s[10], s[11]);
        wc.z = pk2(s[12], s[13]); wc.w = pk2(s[14], s[15]);
        s16x8 pf0 = __builtin_bit_cast(s16x8, wa);
        s16x8 pf1 = __builtin_bit_cast(s16x8, wc);

        __builtin_amdgcn_s_setprio(1);
        accA = __builtin_amdgcn_mfma_f32_32x32x16_bf16(V00[cu], pf0, accA, 0, 0, 0);
        accA = __builtin_amdgcn_mfma_f32_32x32x16_bf16(V01[cu], pf1, accA, 0, 0, 0);
        accB = __builtin_amdgcn_mfma_f32_32x32x16_bf16(V10[cu], pf0, accB, 0, 0, 0);
        accB = __builtin_amdgcn_mfma_f32_32x32x16_bf16(V11[cu], pf1, accB, 0, 0, 0);
        __builtin_amdgcn_s_setprio(0);
    }

    lsum += __shfl_xor(lsum, 32);

    #define WR_SLOT(sidx) do {                                                \
        const int s_ = (sidx);                                                \
        _Pragma("unroll")                                                     \
        for (int r = 0; r < 16; r++) {                                        \
            const int c_ = (r & 3) + 8 * (r >> 2) + 4 * h;                    \
            slds[s_][c_][qt * 32 + lo31]      = accA[r];                      \
            slds[s_][c_ + 32][qt * 32 + lo31] = accB[r];                      \
        }                                                                     \
        if (h == 0) sldl[s_][qt * 32 + lo31] = lsum;                          \
    } while (0)

    #define MRG_SLOT(sidx) do {                                               \
        const int s_ = (sidx);                                                \
        _Pragma("unroll")                                                     \
        for (int r = 0; r < 16; r++) {                                        \
            const int c_ = (r & 3) + 8 * (r >> 2) + 4 * h;                    \
            accA[r] += slds[s_][c_][qt * 32 + lo31];                          \
            accB[r] += slds[s_][c_ + 32][qt * 32 + lo31];                     \
        }                                                                     \
        lsum += sldl[s_][qt * 32 + lo31];                                     \
    } while (0)

    if (u >= 4) WR_SLOT(u - 4);
    __syncthreads();
    if (u < 4) MRG_SLOT(u);
    __syncthreads();
    if (u == 2 || u == 3) WR_SLOT(u - 2);
    __syncthreads();
    if (u < 2) MRG_SLOT(u);
    __syncthreads();
    if (u == 1) WR_SLOT(0);
    __syncthreads();
    if (u == 0) { MRG_SLOT(0); WR_SLOT(0); }
    __syncthreads();

    // ---- fused epilogue: out = gamma*acc/L + x, all 1024 threads ----
    const int c  = t >> 4;              // 0..63
    const int q4 = (t & 15) << 2;       // 0,4,..,60
    const float g = gamma[0];
    const float4 a4 = *(const float4*)&slds[0][c][q4];
    const float g0 = g / sldl[0][q4 + 0];
    const float g1 = g / sldl[0][q4 + 1];
    const float g2 = g / sldl[0][q4 + 2];
    const float g3 = g / sldl[0][q4 + 3];
    const size_t off = (((size_t)b * 64 + c) << 12) + qbase + q4;
    const float4 xv4 = *(const float4*)(x + off);
    float4 o;
    o.x = a4.x * g0 + xv4.x;
    o.y = a4.y * g1 + xv4.y;
    o.z = a4.z * g2 + xv4.z;
    o.w = a4.w * g3 + xv4.w;
    *(float4*)(out + off) = o;
}

// ---------------------------------------------------------------------------
extern "C" void kernel_launch(void* const* d_in, const int* in_sizes, int n_in,
                              void* d_out, int out_size, void* d_ws, size_t ws_size,
                              hipStream_t stream) {
    const float* x     = (const float*)d_in[0];
    const float* Wq    = (const float*)d_in[1];
    const float* bq    = (const float*)d_in[2];
    const float* Wk    = (const float*)d_in[3];
    const float* bk    = (const float*)d_in[4];
    const float* Wv    = (const float*)d_in[5];
    const float* bv    = (const float*)d_in[6];
    const float* gamma = (const float*)d_in[7];
    float* out = (float*)d_out;

    unsigned short* qt2 = (unsigned short*)d_ws;            // 4*4096*16 bf16
    unsigned short* kt2 = qt2 + (size_t)4 * NTOK * 16;      // 4*4096*16 bf16
    unsigned short* vt  = kt2 + (size_t)4 * NTOK * 16;      // 4*4096*64 bf16 (tiled+permuted)

    qkv_kernel<<<128, 256, 0, stream>>>(x, Wq, bq, Wk, bk, Wv, bv, qt2, kt2, vt);
    attn_kernel<<<256, 1024, 0, stream>>>(qt2, kt2, vt, x, gamma, out);
}